// Round 7
// baseline (53.818 us; speedup 1.0000x reference)
//
#include <hip/hip_runtime.h>
#include <math.h>

#define B_N 4096
#define H_N 256
#define I_N 32
#define G3  768

// slots: 128 affinity (8 buckets x 16) + 96 overflow; 224 % 8 == 0
#define NSLOT_AFF 128
#define NSLOT_TOT 224
#define BKT_CAP   16

// ---- workspace layout (bytes) ----
#define WS_IDX     0               // 4096 ints
#define WS_HIST    16384           // 32 ints
#define WS_SLOTS   16640           // 224 ints
#define WS_SORTED  20480           // 4096 ints
#define WS_B4      36864           // 32*256 float4 = 128 KB
#define WS_W5H     167936          // 32*768*256 bf16 = 12 MB (fragment-major)
#define WS_W5L     12750848        // 12 MB
#define WS_NEEDED  25333760

typedef __attribute__((ext_vector_type(8))) short bf16x8_t;
typedef __attribute__((ext_vector_type(4))) float f32x4_t;

__device__ __forceinline__ float sigm(float x) { return 1.0f / (1.0f + expf(-x)); }

__device__ __forceinline__ unsigned short bf16r(float f) {
    union { float f; unsigned u; } x; x.f = f;
    unsigned r = (x.u + 0x7fffu + ((x.u >> 16) & 1u)) >> 16;
    return (unsigned short)r;
}
__device__ __forceinline__ float bf16f(unsigned short h) {
    union { unsigned u; float f; } x; x.u = ((unsigned)h) << 16;
    return x.f;
}

// --- fused aux: repack (768 blk) | bias4 (32 blk) | idx+hist (16 blk) -----
// repack: w[g3][h][e] fp32 -> fragment-major bf16 hi/lo:
//   w5[(e*8+ks)*48 + rowgrp][lane] as uint4; lane = kg*16+m16 holds
//   row = rowgrp*16+m16, k = ks*32+kg*8+0..7.  Each MFMA B-fragment is a
//   contiguous 1 KB block read as lane-consecutive dwordx4 (no gather).
__global__ __launch_bounds__(256) void k_aux(
    const float* __restrict__ w, unsigned short* __restrict__ w5h,
    unsigned short* __restrict__ w5l,
    const float* __restrict__ b_ih, const float* __restrict__ b_hh,
    float4* __restrict__ b4,
    const float* __restrict__ inp, int* __restrict__ idx_arr,
    int* __restrict__ hist)
{
    int bid = blockIdx.x;
    int t = threadIdx.x;
    if (bid < 768) {
        // ---- repack: 8 g3-rows x 32 h x 32 e per block ----
        __shared__ float tl[8 * 1057];      // odd row stride: bank-spread
        int r0 = (bid >> 3) * 8;            // g3-row base (0..760)
        int ks = bid & 7;                   // h-tile = ks*32
#pragma unroll
        for (int it = 0; it < 8; ++it) {
            int f4 = it * 256 + t;          // 0..2047
            int e4 = (f4 & 7) * 4, hh = (f4 >> 3) & 31, r = f4 >> 8;
            float4 v = *(const float4*)(w + ((size_t)(r0 + r) * 256 + ks * 32 + hh) * 32 + e4);
            int bse = r * 1057 + hh * 33 + e4;
            tl[bse] = v.x; tl[bse + 1] = v.y; tl[bse + 2] = v.z; tl[bse + 3] = v.w;
        }
        __syncthreads();
        int rowgrp = r0 >> 4;
        int mbase = r0 & 15;                // 0 or 8
#pragma unroll
        for (int it = 0; it < 4; ++it) {
            int c = it * 256 + t;           // 0..1023
            int m8 = c & 7, kg = (c >> 3) & 3, e = c >> 5;
            union { unsigned short us[8]; uint4 v; } hi, lo;
#pragma unroll
            for (int t8 = 0; t8 < 8; ++t8) {
                float f = tl[m8 * 1057 + (kg * 8 + t8) * 33 + e];
                unsigned short h = bf16r(f);
                hi.us[t8] = h; lo.us[t8] = bf16r(f - bf16f(h));
            }
            size_t chunk = ((size_t)(e * 8 + ks) * 48 + rowgrp) * 64 + kg * 16 + mbase + m8;
            ((uint4*)w5h)[chunk] = hi.v;
            ((uint4*)w5l)[chunk] = lo.v;
        }
    } else if (bid < 800) {
        // ---- bias4: b4[e][tt] = {r_sum, u_sum, n_ih, n_hh} ----
        int bb = bid - 768;
        int e = t & 31;
        int tt = bb * 8 + (t >> 5);
        float r = b_ih[tt * 32 + e] + b_hh[tt * 32 + e];
        float u = b_ih[(256 + tt) * 32 + e] + b_hh[(256 + tt) * 32 + e];
        float ni = b_ih[(512 + tt) * 32 + e];
        float nh = b_hh[(512 + tt) * 32 + e];
        float4 o = {r, u, ni, nh};
        b4[e * 256 + tt] = o;
    } else {
        // ---- one-hot -> expert index + global histogram ----
        int b = (bid - 800) * 256 + t;
        const float4* p = (const float4*)(inp + (size_t)b * I_N);
        int idx = 0;
#pragma unroll
        for (int k = 0; k < 8; ++k) {
            float4 v = p[k];
            if (v.x > 0.5f) idx = k * 4 + 0;
            if (v.y > 0.5f) idx = k * 4 + 1;
            if (v.z > 0.5f) idx = k * 4 + 2;
            if (v.w > 0.5f) idx = k * 4 + 3;
        }
        idx_arr[b] = idx;
        atomicAdd(hist + idx, 1);
    }
}

// --- prefix + XCD-affine M=64 chunk plan + scatter (1 block) --------------
// item = (e<<19)|(base<<7)|M, M<=64. Expert e's chunks at slots s%8==e%8 so
// blockIdx%8 (round-robin XCD) keeps each expert's w5 slice in ONE XCD L2.
__global__ void k_plan(const int* __restrict__ hist, const int* __restrict__ idx_arr,
                       int* __restrict__ slots, int* __restrict__ sorted) {
    __shared__ int offs_l[32], lcur[32];
    __shared__ int bcur[8], ovf;
    int t = threadIdx.x;
    if (t < 8) bcur[t] = 0;
    if (t == 0) ovf = 0;
    if (t == 0) {
        int run = 0;
        for (int e = 0; e < 32; ++e) { offs_l[e] = run; run += hist[e]; }
    }
    __syncthreads();
    if (t < 32) lcur[t] = offs_l[t];
    for (int s = t; s < NSLOT_TOT; s += 512) slots[s] = -1;
    __syncthreads();
    // chunk plan (M=64)
    for (int c = t; c < 32 * 64; c += 512) {
        int e = c >> 6, ch = c & 63;
        int cnt = hist[e];
        if (ch * 64 < cnt) {
            int M = cnt - ch * 64; if (M > 64) M = 64;
            int base = offs_l[e] + ch * 64;
            int item = (e << 19) | (base << 7) | M;
            int bkt = e & 7;
            int j = atomicAdd(&bcur[bkt], 1);
            if (j < BKT_CAP) slots[bkt + 8 * j] = item;
            else { int k = atomicAdd(&ovf, 1); slots[NSLOT_AFF + k] = item; }
        }
    }
    __syncthreads();
    // scatter into expert-sorted order
    for (int b = t; b < B_N; b += 512) {
        int e = idx_arr[b];
        int pos = atomicAdd(&lcur[e], 1);
        sorted[pos] = b;
    }
}

// --- grouped MFMA GEMM + fused GRU epilogue, M=64 -------------------------
// 4 waves/block; wave wv covers unit group q = blockIdx.y*4+wv (16 units) x 3
// gates x 4 A-tiles. A staged fp32->bf16 hi/lo in swizzled LDS; B read as
// contiguous 1 KB fragment streams; each fragment feeds 4 A-tiles (4x reuse).
__global__ __launch_bounds__(256, 2) void k_gemm_mfma(
    const unsigned short* __restrict__ w5h, const unsigned short* __restrict__ w5l,
    const float* __restrict__ hx, const float4* __restrict__ b4,
    const int* __restrict__ sorted, const int* __restrict__ slots,
    float* __restrict__ out)
{
    int item = slots[blockIdx.x];
    if (item < 0) return;
    int e = item >> 19, base = (item >> 7) & 0xfff, M = item & 0x7f;
    int ntiles = (M + 15) >> 4;           // 1..4, wave-uniform

    __shared__ unsigned short Ah[64 * 256];   // 32 KB
    __shared__ unsigned short Al[64 * 256];   // 32 KB
    __shared__ int bids[64];

    int t = threadIdx.x;
    // stage A: two passes of 32 rows; row = t>>3, c8 = t&7 owns k [c8*32,+32)
#pragma unroll
    for (int pas = 0; pas < 2; ++pas) {
        int row = (t >> 3) + pas * 32, c8 = t & 7;
        int b = (row < M) ? sorted[base + row] : -1;
        if (c8 == 0) bids[row] = b;
        if (b >= 0) {
            const float* src = hx + ((size_t)b << 8) + c8 * 32;
            float fv[32];
#pragma unroll
            for (int p = 0; p < 8; ++p)
                *(float4*)&fv[p * 4] = *(const float4*)(src + p * 4);
#pragma unroll
            for (int p = 0; p < 4; ++p) {
                union { unsigned short us[8]; uint4 v; } hu, lu;
#pragma unroll
                for (int jj = 0; jj < 8; ++jj) {
                    float f = fv[p * 8 + jj];
                    unsigned short h = bf16r(f);
                    hu.us[jj] = h; lu.us[jj] = bf16r(f - bf16f(h));
                }
                int col = (c8 * 4 + p) ^ (row & 7);
                *(uint4*)&Ah[row * 256 + col * 8] = hu.v;
                *(uint4*)&Al[row * 256 + col * 8] = lu.v;
            }
        } else {
            uint4 z = {0, 0, 0, 0};
#pragma unroll
            for (int p = 0; p < 4; ++p) {
                int col = (c8 * 4 + p) ^ (row & 7);
                *(uint4*)&Ah[row * 256 + col * 8] = z;
                *(uint4*)&Al[row * 256 + col * 8] = z;
            }
        }
    }
    __syncthreads();

    int lane = t & 63, wv = t >> 6;
    int m16 = lane & 15, kg = lane >> 4;
    int q = blockIdx.y * 4 + wv;         // unit group 0..15

    f32x4_t acc[4][3];
#pragma unroll
    for (int tl2 = 0; tl2 < 4; ++tl2)
#pragma unroll
        for (int g = 0; g < 3; ++g) acc[tl2][g] = (f32x4_t){0.f, 0.f, 0.f, 0.f};

    // fragment id = (e*8+ks)*48 + g*16 + q; 512 ush per fragment
    const unsigned short* bh_p = w5h + ((size_t)(e * 8) * 48 + q) * 512 + (size_t)lane * 8;
    const unsigned short* bl_p = w5l + ((size_t)(e * 8) * 48 + q) * 512 + (size_t)lane * 8;

#pragma unroll
    for (int ks = 0; ks < 8; ++ks) {
        int ch = ks * 4 + kg;
        int sw = (ch ^ (m16 & 7)) << 3;
        bf16x8_t a_h[4], a_l[4];
#pragma unroll
        for (int tl2 = 0; tl2 < 4; ++tl2) {
            a_h[tl2] = *(const bf16x8_t*)&Ah[(tl2 * 16 + m16) * 256 + sw];
            a_l[tl2] = *(const bf16x8_t*)&Al[(tl2 * 16 + m16) * 256 + sw];
        }
#pragma unroll
        for (int g = 0; g < 3; ++g) {
            size_t foff = ((size_t)ks * 48 + g * 16) * 512;
            bf16x8_t b_h = *(const bf16x8_t*)(bh_p + foff);
            bf16x8_t b_l = *(const bf16x8_t*)(bl_p + foff);
#pragma unroll
            for (int tl2 = 0; tl2 < 4; ++tl2) {
                if (tl2 < ntiles) {
                    acc[tl2][g] = __builtin_amdgcn_mfma_f32_16x16x32_bf16(a_h[tl2], b_h, acc[tl2][g], 0, 0, 0);
                    acc[tl2][g] = __builtin_amdgcn_mfma_f32_16x16x32_bf16(a_l[tl2], b_h, acc[tl2][g], 0, 0, 0);
                    acc[tl2][g] = __builtin_amdgcn_mfma_f32_16x16x32_bf16(a_h[tl2], b_l, acc[tl2][g], 0, 0, 0);
                }
            }
        }
    }

    // fused GRU epilogue: C row=(lane>>4)*4+reg (batch m), col=lane&15 (unit)
    int mg = (lane >> 4) * 4;
    int tt = q * 16 + m16;
    float4 bs = b4[e * 256 + tt];
#pragma unroll
    for (int tl2 = 0; tl2 < 4; ++tl2) {
#pragma unroll
        for (int i = 0; i < 4; ++i) {
            int mr = tl2 * 16 + mg + i;
            if (mr < M) {
                int b = bids[mr];
                float x = hx[(size_t)b * 256 + tt];
                float r = sigm(acc[tl2][0][i] + bs.x);
                float u = sigm(acc[tl2][1][i] + bs.y);
                float n = tanhf(bs.z + r * (acc[tl2][2][i] + bs.w));
                out[(size_t)b * 256 + tt] = u * x + (1.0f - u) * n;
            }
        }
    }
}

// --- fallback: correct but slow, if ws too small --------------------------
__global__ void k_naive(const float* __restrict__ inp, const float* __restrict__ hx,
                        const float* __restrict__ w, const float* __restrict__ b_ih,
                        const float* __restrict__ b_hh, float* __restrict__ out) {
    int b = blockIdx.x;
    int t = threadIdx.x;
    __shared__ float sx[H_N];
    __shared__ int sidx;
    if (t == 0) {
        int idx = 0;
        for (int i = 0; i < I_N; ++i)
            if (inp[b * I_N + i] > 0.5f) idx = i;
        sidx = idx;
    }
    sx[t] = hx[b * H_N + t];
    __syncthreads();
    int i = sidx;
    float a0 = 0.f, a1 = 0.f, a2 = 0.f;
    for (int h = 0; h < H_N; ++h) {
        float xv = sx[h];
        a0 = fmaf(w[(t * H_N + h) * I_N + i], xv, a0);
        a1 = fmaf(w[((256 + t) * H_N + h) * I_N + i], xv, a1);
        a2 = fmaf(w[((512 + t) * H_N + h) * I_N + i], xv, a2);
    }
    float r = sigm(b_ih[t * I_N + i] + a0 + b_hh[t * I_N + i]);
    float u = sigm(b_ih[(256 + t) * I_N + i] + a1 + b_hh[(256 + t) * I_N + i]);
    float n = tanhf(b_ih[(512 + t) * I_N + i] + r * (a2 + b_hh[(512 + t) * I_N + i]));
    out[b * H_N + t] = u * sx[t] + (1.0f - u) * n;
}

extern "C" void kernel_launch(void* const* d_in, const int* in_sizes, int n_in,
                              void* d_out, int out_size, void* d_ws, size_t ws_size,
                              hipStream_t stream) {
    const float* inp  = (const float*)d_in[0];
    const float* hx   = (const float*)d_in[1];
    const float* w    = (const float*)d_in[2];
    const float* b_ih = (const float*)d_in[3];
    const float* b_hh = (const float*)d_in[4];
    float* out = (float*)d_out;

    if (ws_size < (size_t)WS_NEEDED) {
        k_naive<<<B_N, H_N, 0, stream>>>(inp, hx, w, b_ih, b_hh, out);
        return;
    }

    char* ws = (char*)d_ws;
    int* idx_arr = (int*)(ws + WS_IDX);
    int* hist    = (int*)(ws + WS_HIST);
    int* slots   = (int*)(ws + WS_SLOTS);
    int* sorted  = (int*)(ws + WS_SORTED);
    float4* b4   = (float4*)(ws + WS_B4);
    unsigned short* w5h = (unsigned short*)(ws + WS_W5H);
    unsigned short* w5l = (unsigned short*)(ws + WS_W5L);

    hipMemsetAsync(hist, 0, 128, stream);
    k_aux<<<816, 256, 0, stream>>>(w, w5h, w5l, b_ih, b_hh, b4, inp, idx_arr, hist);
    k_plan<<<1, 512, 0, stream>>>(hist, idx_arr, slots, sorted);
    k_gemm_mfma<<<dim3(NSLOT_TOT, 4), 256, 0, stream>>>(w5h, w5l, hx, b4,
                                                        sorted, slots, out);
}

// Round 8
// 37.957 us; speedup vs baseline: 1.4179x; 1.4179x over previous
//
#include <hip/hip_runtime.h>
#include <math.h>

#define B_N 4096
#define H_N 256
#define I_N 32
#define G3  768

// slots: 192 affinity slots (8 buckets x 24) + 144 overflow; 336 % 8 == 0
#define NSLOT_AFF 192
#define NSLOT_TOT 336
#define BKT_CAP   24

// ---- workspace layout (bytes) ----
#define WS_IDX     0               // 4096 ints
#define WS_SLOTS   16640           // 336 ints
#define WS_SORTED  20480           // 4096 ints
#define WS_B4      36864           // 32*256 float4 = 128 KB
#define WS_W5      167936          // 32*768*256 fp16 = 12.58 MB (fragment-major)
#define WS_NEEDED  12750848

typedef __attribute__((ext_vector_type(8))) _Float16 f16x8_t;
typedef __attribute__((ext_vector_type(4))) float f32x4_t;

__device__ __forceinline__ float sigm(float x) { return 1.0f / (1.0f + expf(-x)); }

// --- one-hot -> expert index ----------------------------------------------
__global__ void k_idx(const float* __restrict__ inp, int* __restrict__ idx_arr) {
    int b = blockIdx.x * blockDim.x + threadIdx.x;
    if (b >= B_N) return;
    const float4* p = (const float4*)(inp + (size_t)b * I_N);
    int idx = 0;
#pragma unroll
    for (int k = 0; k < 8; ++k) {
        float4 v = p[k];
        if (v.x > 0.5f) idx = k * 4 + 0;
        if (v.y > 0.5f) idx = k * 4 + 1;
        if (v.z > 0.5f) idx = k * 4 + 2;
        if (v.w > 0.5f) idx = k * 4 + 3;
    }
    idx_arr[b] = idx;
}

// --- histogram + prefix + XCD-affine M=32 chunk plan + scatter (1 block) --
// item = (e<<18)|(base<<6)|M, M<=32. Expert e's chunks at slots s%8==e%8 so
// blockIdx%8 (round-robin XCD) keeps each expert's w5 slice in ONE XCD L2.
__global__ void k_plan(const int* __restrict__ idx_arr, int* __restrict__ slots,
                       int* __restrict__ sorted) {
    __shared__ int hist[32], offs_l[32], lcur[32];
    __shared__ int bcur[8], ovf;
    int t = threadIdx.x;
    if (t < 32) hist[t] = 0;
    if (t < 8) bcur[t] = 0;
    if (t == 0) ovf = 0;
    __syncthreads();
    for (int i = t; i < B_N; i += 512) atomicAdd(&hist[idx_arr[i]], 1);
    __syncthreads();
    if (t == 0) {
        int run = 0;
        for (int e = 0; e < 32; ++e) { offs_l[e] = run; run += hist[e]; }
    }
    __syncthreads();
    if (t < 32) lcur[t] = offs_l[t];
    for (int s = t; s < NSLOT_TOT; s += 512) slots[s] = -1;
    __syncthreads();
    // chunk plan (M=32)
    for (int c = t; c < 32 * 128; c += 512) {
        int e = c >> 7, ch = c & 127;
        int cnt = hist[e];
        if (ch * 32 < cnt) {
            int M = cnt - ch * 32; if (M > 32) M = 32;
            int base = offs_l[e] + ch * 32;
            int item = (e << 18) | (base << 6) | M;
            int bkt = e & 7;
            int j = atomicAdd(&bcur[bkt], 1);
            if (j < BKT_CAP) slots[bkt + 8 * j] = item;
            else { int k = atomicAdd(&ovf, 1); slots[NSLOT_AFF + k] = item; }
        }
    }
    // scatter into expert-sorted order
    for (int b = t; b < B_N; b += 512) {
        int e = idx_arr[b];
        int pos = atomicAdd(&lcur[e], 1);
        sorted[pos] = b;
    }
}

// --- fused aux kernel: repack (768 blocks) | bias4 (32 blocks) ------------
// repack: w[g3][h][e] fp32 -> fragment-major SINGLE fp16:
//   w5[(e*8+ks)*48 + rowgrp][lane] as uint4; lane = kg*16+m16 holds
//   row = rowgrp*16+m16, k = ks*32+kg*8+0..7.  Each MFMA B-fragment is a
//   contiguous 1 KB block read as lane-consecutive dwordx4 (no gather).
__global__ __launch_bounds__(256) void k_aux(
    const float* __restrict__ w, unsigned short* __restrict__ w5,
    const float* __restrict__ b_ih, const float* __restrict__ b_hh,
    float4* __restrict__ b4)
{
    int bid = blockIdx.x;
    int t = threadIdx.x;
    if (bid < 768) {
        // ---- repack: 8 g3-rows x 32 h x 32 e per block ----
        __shared__ float tl[8 * 1057];      // odd row stride: bank-spread
        int r0 = (bid >> 3) * 8;            // g3-row base (0..760)
        int ks = bid & 7;                   // h-tile = ks*32
#pragma unroll
        for (int it = 0; it < 8; ++it) {
            int f4 = it * 256 + t;          // 0..2047
            int e4 = (f4 & 7) * 4, hh = (f4 >> 3) & 31, r = f4 >> 8;
            float4 v = *(const float4*)(w + ((size_t)(r0 + r) * 256 + ks * 32 + hh) * 32 + e4);
            int bse = r * 1057 + hh * 33 + e4;
            tl[bse] = v.x; tl[bse + 1] = v.y; tl[bse + 2] = v.z; tl[bse + 3] = v.w;
        }
        __syncthreads();
        int rowgrp = r0 >> 4;
        int mbase = r0 & 15;                // 0 or 8
#pragma unroll
        for (int it = 0; it < 4; ++it) {
            int c = it * 256 + t;           // 0..1023
            int m8 = c & 7, kg = (c >> 3) & 3, e = c >> 5;
            union { _Float16 h[8]; uint4 v; } hi;
#pragma unroll
            for (int t8 = 0; t8 < 8; ++t8) {
                float f = tl[m8 * 1057 + (kg * 8 + t8) * 33 + e];
                hi.h[t8] = (_Float16)f;
            }
            size_t chunk = ((size_t)(e * 8 + ks) * 48 + rowgrp) * 64 + kg * 16 + mbase + m8;
            ((uint4*)w5)[chunk] = hi.v;
        }
    } else {
        // ---- bias4: b4[e][tt] = {r_sum, u_sum, n_ih, n_hh} ----
        int bb = bid - 768;
        int e = t & 31;
        int tt = bb * 8 + (t >> 5);
        float r = b_ih[tt * 32 + e] + b_hh[tt * 32 + e];
        float u = b_ih[(256 + tt) * 32 + e] + b_hh[(256 + tt) * 32 + e];
        float ni = b_ih[(512 + tt) * 32 + e];
        float nh = b_hh[(512 + tt) * 32 + e];
        float4 o = {r, u, ni, nh};
        b4[e * 256 + tt] = o;
    }
}

// --- grouped MFMA GEMM + fused GRU epilogue, M=32, fp16 -------------------
// 4 waves/block; wave wv covers unit group q = blockIdx.y*4+wv (16 units) x 3
// gates x 2 A-tiles. A staged fp32 -> fp16 hi/lo (captures hx to 2^-22) in
// swizzled LDS; W single fp16 (rel err 2^-12). B fragments are contiguous
// 1 KB streams; each feeds 2 A-tiles x 2 split terms = 4 MFMAs.
__global__ __launch_bounds__(256) void k_gemm_mfma(
    const unsigned short* __restrict__ w5,
    const float* __restrict__ hx, const float4* __restrict__ b4,
    const int* __restrict__ sorted, const int* __restrict__ slots,
    float* __restrict__ out)
{
    int item = slots[blockIdx.x];
    if (item < 0) return;
    int e = item >> 18, base = (item >> 6) & 0xfff, M = item & 63;

    __shared__ _Float16 Ah[32 * 256];   // 16 KB
    __shared__ _Float16 Al[32 * 256];   // 16 KB
    __shared__ int bids[32];

    int t = threadIdx.x;
    {   // stage A: row = t>>3 (0..31), c8 = t&7 owns k in [c8*32, +32)
        int row = t >> 3, c8 = t & 7;
        int b = (row < M) ? sorted[base + row] : -1;
        if (c8 == 0) bids[row] = b;
        if (b >= 0) {
            const float* src = hx + ((size_t)b << 8) + c8 * 32;
            float fv[32];
#pragma unroll
            for (int p = 0; p < 8; ++p)
                *(float4*)&fv[p * 4] = *(const float4*)(src + p * 4);
#pragma unroll
            for (int p = 0; p < 4; ++p) {
                union { _Float16 h[8]; uint4 v; } hu, lu;
#pragma unroll
                for (int jj = 0; jj < 8; ++jj) {
                    float f = fv[p * 8 + jj];
                    _Float16 h = (_Float16)f;
                    hu.h[jj] = h;
                    lu.h[jj] = (_Float16)(f - (float)h);
                }
                int col = (c8 * 4 + p) ^ (row & 7);
                *(uint4*)&Ah[row * 256 + col * 8] = hu.v;
                *(uint4*)&Al[row * 256 + col * 8] = lu.v;
            }
        } else {
            uint4 z = {0, 0, 0, 0};
#pragma unroll
            for (int p = 0; p < 4; ++p) {
                int col = (c8 * 4 + p) ^ (row & 7);
                *(uint4*)&Ah[row * 256 + col * 8] = z;
                *(uint4*)&Al[row * 256 + col * 8] = z;
            }
        }
    }
    __syncthreads();

    int lane = t & 63, wv = t >> 6;
    int m16 = lane & 15, kg = lane >> 4;
    int q = blockIdx.y * 4 + wv;         // unit group 0..15

    f32x4_t acc[2][3];
#pragma unroll
    for (int tl2 = 0; tl2 < 2; ++tl2)
#pragma unroll
        for (int g = 0; g < 3; ++g) acc[tl2][g] = (f32x4_t){0.f, 0.f, 0.f, 0.f};

    // fragment id = (e*8+ks)*48 + g*16 + q; 512 halfs per fragment
    const unsigned short* b_p = w5 + ((size_t)(e * 8) * 48 + q) * 512 + (size_t)lane * 8;

#pragma unroll
    for (int ks = 0; ks < 8; ++ks) {
        int ch = ks * 4 + kg;
        int sw = (ch ^ (m16 & 7)) << 3;
        f16x8_t a_h0 = *(const f16x8_t*)&Ah[m16 * 256 + sw];
        f16x8_t a_l0 = *(const f16x8_t*)&Al[m16 * 256 + sw];
        f16x8_t a_h1 = *(const f16x8_t*)&Ah[(16 + m16) * 256 + sw];
        f16x8_t a_l1 = *(const f16x8_t*)&Al[(16 + m16) * 256 + sw];
#pragma unroll
        for (int g = 0; g < 3; ++g) {
            size_t foff = ((size_t)ks * 48 + g * 16) * 512;
            f16x8_t b_h = *(const f16x8_t*)(b_p + foff);
            acc[0][g] = __builtin_amdgcn_mfma_f32_16x16x32_f16(a_h0, b_h, acc[0][g], 0, 0, 0);
            acc[0][g] = __builtin_amdgcn_mfma_f32_16x16x32_f16(a_l0, b_h, acc[0][g], 0, 0, 0);
            acc[1][g] = __builtin_amdgcn_mfma_f32_16x16x32_f16(a_h1, b_h, acc[1][g], 0, 0, 0);
            acc[1][g] = __builtin_amdgcn_mfma_f32_16x16x32_f16(a_l1, b_h, acc[1][g], 0, 0, 0);
        }
    }

    // fused GRU epilogue: C row=(lane>>4)*4+reg (batch m), col=lane&15 (unit)
    int mg = (lane >> 4) * 4;
    int tt = q * 16 + m16;
    float4 bs = b4[e * 256 + tt];
#pragma unroll
    for (int tl2 = 0; tl2 < 2; ++tl2) {
#pragma unroll
        for (int i = 0; i < 4; ++i) {
            int mr = tl2 * 16 + mg + i;
            if (mr < M) {
                int b = bids[mr];
                float x = hx[(size_t)b * 256 + tt];
                float r = sigm(acc[tl2][0][i] + bs.x);
                float u = sigm(acc[tl2][1][i] + bs.y);
                float n = tanhf(bs.z + r * (acc[tl2][2][i] + bs.w));
                out[(size_t)b * 256 + tt] = u * x + (1.0f - u) * n;
            }
        }
    }
}

// --- fallback: correct but slow, if ws too small --------------------------
__global__ void k_naive(const float* __restrict__ inp, const float* __restrict__ hx,
                        const float* __restrict__ w, const float* __restrict__ b_ih,
                        const float* __restrict__ b_hh, float* __restrict__ out) {
    int b = blockIdx.x;
    int t = threadIdx.x;
    __shared__ float sx[H_N];
    __shared__ int sidx;
    if (t == 0) {
        int idx = 0;
        for (int i = 0; i < I_N; ++i)
            if (inp[b * I_N + i] > 0.5f) idx = i;
        sidx = idx;
    }
    sx[t] = hx[b * H_N + t];
    __syncthreads();
    int i = sidx;
    float a0 = 0.f, a1 = 0.f, a2 = 0.f;
    for (int h = 0; h < H_N; ++h) {
        float xv = sx[h];
        a0 = fmaf(w[(t * H_N + h) * I_N + i], xv, a0);
        a1 = fmaf(w[((256 + t) * H_N + h) * I_N + i], xv, a1);
        a2 = fmaf(w[((512 + t) * H_N + h) * I_N + i], xv, a2);
    }
    float r = sigm(b_ih[t * I_N + i] + a0 + b_hh[t * I_N + i]);
    float u = sigm(b_ih[(256 + t) * I_N + i] + a1 + b_hh[(256 + t) * I_N + i]);
    float n = tanhf(b_ih[(512 + t) * I_N + i] + r * (a2 + b_hh[(512 + t) * I_N + i]));
    out[b * H_N + t] = u * sx[t] + (1.0f - u) * n;
}

extern "C" void kernel_launch(void* const* d_in, const int* in_sizes, int n_in,
                              void* d_out, int out_size, void* d_ws, size_t ws_size,
                              hipStream_t stream) {
    const float* inp  = (const float*)d_in[0];
    const float* hx   = (const float*)d_in[1];
    const float* w    = (const float*)d_in[2];
    const float* b_ih = (const float*)d_in[3];
    const float* b_hh = (const float*)d_in[4];
    float* out = (float*)d_out;

    if (ws_size < (size_t)WS_NEEDED) {
        k_naive<<<B_N, H_N, 0, stream>>>(inp, hx, w, b_ih, b_hh, out);
        return;
    }

    char* ws = (char*)d_ws;
    int* idx_arr = (int*)(ws + WS_IDX);
    int* slots   = (int*)(ws + WS_SLOTS);
    int* sorted  = (int*)(ws + WS_SORTED);
    float4* b4   = (float4*)(ws + WS_B4);
    unsigned short* w5 = (unsigned short*)(ws + WS_W5);

    k_idx<<<B_N / 256, 256, 0, stream>>>(inp, idx_arr);
    k_plan<<<1, 512, 0, stream>>>(idx_arr, slots, sorted);
    k_aux<<<800, 256, 0, stream>>>(w, w5, b_ih, b_hh, b4);
    k_gemm_mfma<<<dim3(NSLOT_TOT, 4), 256, 0, stream>>>(w5, hx, b4,
                                                        sorted, slots, out);
}

// Round 9
// 30.261 us; speedup vs baseline: 1.7784x; 1.2543x over previous
//
#include <hip/hip_runtime.h>
#include <math.h>

#define B_N 4096
#define H_N 256
#define I_N 32
#define G3  768

// slots: 192 affinity slots (8 buckets x 24) + 144 overflow; 336 % 8 == 0
#define NSLOT_AFF 192
#define NSLOT_TOT 336
#define BKT_CAP   24

// ---- workspace layout (bytes) ----
#define WS_IDX     0               // 4096 ints
#define WS_SLOTS   16640           // 336 ints
#define WS_SORTED  20480           // 4096 ints
#define WS_B4      36864           // 32*256 float4 = 128 KB
#define WS_W5      167936          // 32*768*256 fp16 = 12.58 MB (fragment-major)
#define WS_NEEDED  12750848

typedef __attribute__((ext_vector_type(8))) _Float16 f16x8_t;
typedef __attribute__((ext_vector_type(4))) float f32x4_t;

__device__ __forceinline__ float sigm(float x) { return 1.0f / (1.0f + expf(-x)); }

// --- fused aux: repack (768 blk) | bias4 (32 blk) | idx (16 blk) ----------
// repack: w[g3][h][e] fp32 -> fragment-major SINGLE fp16:
//   w5[(e*8+ks)*48 + rowgrp][lane] as uint4; lane = kg*16+m16 holds
//   row = rowgrp*16+m16, k = ks*32+kg*8+0..7.  Each MFMA B-fragment is a
//   contiguous 1 KB block read as lane-consecutive dwordx4 (no gather).
__global__ __launch_bounds__(256) void k_aux(
    const float* __restrict__ w, unsigned short* __restrict__ w5,
    const float* __restrict__ b_ih, const float* __restrict__ b_hh,
    float4* __restrict__ b4,
    const float* __restrict__ inp, int* __restrict__ idx_arr)
{
    int bid = blockIdx.x;
    int t = threadIdx.x;
    if (bid < 768) {
        // ---- repack: 8 g3-rows x 32 h x 32 e per block ----
        __shared__ float tl[8 * 1057];      // odd row stride: bank-spread
        int r0 = (bid >> 3) * 8;            // g3-row base (0..760)
        int ks = bid & 7;                   // h-tile = ks*32
#pragma unroll
        for (int it = 0; it < 8; ++it) {
            int f4 = it * 256 + t;          // 0..2047
            int e4 = (f4 & 7) * 4, hh = (f4 >> 3) & 31, r = f4 >> 8;
            float4 v = *(const float4*)(w + ((size_t)(r0 + r) * 256 + ks * 32 + hh) * 32 + e4);
            int bse = r * 1057 + hh * 33 + e4;
            tl[bse] = v.x; tl[bse + 1] = v.y; tl[bse + 2] = v.z; tl[bse + 3] = v.w;
        }
        __syncthreads();
        int rowgrp = r0 >> 4;
        int mbase = r0 & 15;                // 0 or 8
#pragma unroll
        for (int it = 0; it < 4; ++it) {
            int c = it * 256 + t;           // 0..1023
            int m8 = c & 7, kg = (c >> 3) & 3, e = c >> 5;
            union { _Float16 h[8]; uint4 v; } hi;
#pragma unroll
            for (int t8 = 0; t8 < 8; ++t8) {
                float f = tl[m8 * 1057 + (kg * 8 + t8) * 33 + e];
                hi.h[t8] = (_Float16)f;
            }
            size_t chunk = ((size_t)(e * 8 + ks) * 48 + rowgrp) * 64 + kg * 16 + mbase + m8;
            ((uint4*)w5)[chunk] = hi.v;
        }
    } else if (bid < 800) {
        // ---- bias4: b4[e][tt] = {r_sum, u_sum, n_ih, n_hh} ----
        int bb = bid - 768;
        int e = t & 31;
        int tt = bb * 8 + (t >> 5);
        float r = b_ih[tt * 32 + e] + b_hh[tt * 32 + e];
        float u = b_ih[(256 + tt) * 32 + e] + b_hh[(256 + tt) * 32 + e];
        float ni = b_ih[(512 + tt) * 32 + e];
        float nh = b_hh[(512 + tt) * 32 + e];
        float4 o = {r, u, ni, nh};
        b4[e * 256 + tt] = o;
    } else {
        // ---- one-hot -> expert index ----
        int b = (bid - 800) * 256 + t;
        const float4* p = (const float4*)(inp + (size_t)b * I_N);
        int idx = 0;
#pragma unroll
        for (int k = 0; k < 8; ++k) {
            float4 v = p[k];
            if (v.x > 0.5f) idx = k * 4 + 0;
            if (v.y > 0.5f) idx = k * 4 + 1;
            if (v.z > 0.5f) idx = k * 4 + 2;
            if (v.w > 0.5f) idx = k * 4 + 3;
        }
        idx_arr[b] = idx;
    }
}

// --- histogram + prefix + XCD-affine M=32 chunk plan + scatter (1 block) --
// item = (e<<18)|(base<<6)|M, M<=32. Expert e's chunks at slots s%8==e%8 so
// blockIdx%8 (round-robin XCD) keeps each expert's w5 slice in ONE XCD L2.
__global__ void k_plan(const int* __restrict__ idx_arr, int* __restrict__ slots,
                       int* __restrict__ sorted) {
    __shared__ int hist[32], offs_l[32], lcur[32];
    __shared__ int bcur[8], ovf;
    int t = threadIdx.x;
    if (t < 32) hist[t] = 0;
    if (t < 8) bcur[t] = 0;
    if (t == 0) ovf = 0;
    __syncthreads();
    for (int i = t; i < B_N; i += 512) atomicAdd(&hist[idx_arr[i]], 1);
    __syncthreads();
    if (t == 0) {
        int run = 0;
        for (int e = 0; e < 32; ++e) { offs_l[e] = run; run += hist[e]; }
    }
    __syncthreads();
    if (t < 32) lcur[t] = offs_l[t];
    for (int s = t; s < NSLOT_TOT; s += 512) slots[s] = -1;
    __syncthreads();
    // chunk plan (M=32)
    for (int c = t; c < 32 * 128; c += 512) {
        int e = c >> 7, ch = c & 127;
        int cnt = hist[e];
        if (ch * 32 < cnt) {
            int M = cnt - ch * 32; if (M > 32) M = 32;
            int base = offs_l[e] + ch * 32;
            int item = (e << 18) | (base << 6) | M;
            int bkt = e & 7;
            int j = atomicAdd(&bcur[bkt], 1);
            if (j < BKT_CAP) slots[bkt + 8 * j] = item;
            else { int k = atomicAdd(&ovf, 1); slots[NSLOT_AFF + k] = item; }
        }
    }
    // scatter into expert-sorted order
    for (int b = t; b < B_N; b += 512) {
        int e = idx_arr[b];
        int pos = atomicAdd(&lcur[e], 1);
        sorted[pos] = b;
    }
}

// --- grouped MFMA GEMM + fused GRU epilogue, M=32, all-fp16 ---------------
// 4 waves/block; wave wv covers unit group q = blockIdx.y*4+wv (16 units) x 3
// gates x 2 A-tiles. A fp32 -> single fp16 in swizzled LDS (16 KB); W single
// fp16. B fragments are contiguous 1 KB streams; 1 MFMA per (tile, gate).
__global__ __launch_bounds__(256) void k_gemm_mfma(
    const unsigned short* __restrict__ w5,
    const float* __restrict__ hx, const float4* __restrict__ b4,
    const int* __restrict__ sorted, const int* __restrict__ slots,
    float* __restrict__ out)
{
    int item = slots[blockIdx.x];
    if (item < 0) return;
    int e = item >> 18, base = (item >> 6) & 0xfff, M = item & 63;

    __shared__ _Float16 Ah[32 * 256];   // 16 KB
    __shared__ int bids[32];

    int t = threadIdx.x;
    {   // stage A: row = t>>3 (0..31), c8 = t&7 owns k in [c8*32, +32)
        int row = t >> 3, c8 = t & 7;
        int b = (row < M) ? sorted[base + row] : -1;
        if (c8 == 0) bids[row] = b;
        if (b >= 0) {
            const float* src = hx + ((size_t)b << 8) + c8 * 32;
            float fv[32];
#pragma unroll
            for (int p = 0; p < 8; ++p)
                *(float4*)&fv[p * 4] = *(const float4*)(src + p * 4);
#pragma unroll
            for (int p = 0; p < 4; ++p) {
                union { _Float16 h[8]; uint4 v; } hu;
#pragma unroll
                for (int jj = 0; jj < 8; ++jj)
                    hu.h[jj] = (_Float16)fv[p * 8 + jj];
                int col = (c8 * 4 + p) ^ (row & 7);
                *(uint4*)&Ah[row * 256 + col * 8] = hu.v;
            }
        } else {
            uint4 z = {0, 0, 0, 0};
#pragma unroll
            for (int p = 0; p < 4; ++p) {
                int col = (c8 * 4 + p) ^ (row & 7);
                *(uint4*)&Ah[row * 256 + col * 8] = z;
            }
        }
    }
    __syncthreads();

    int lane = t & 63, wv = t >> 6;
    int m16 = lane & 15, kg = lane >> 4;
    int q = blockIdx.y * 4 + wv;         // unit group 0..15

    f32x4_t acc[2][3];
#pragma unroll
    for (int tl2 = 0; tl2 < 2; ++tl2)
#pragma unroll
        for (int g = 0; g < 3; ++g) acc[tl2][g] = (f32x4_t){0.f, 0.f, 0.f, 0.f};

    // fragment id = (e*8+ks)*48 + g*16 + q; 512 halfs per fragment
    const unsigned short* b_p = w5 + ((size_t)(e * 8) * 48 + q) * 512 + (size_t)lane * 8;

#pragma unroll
    for (int ks = 0; ks < 8; ++ks) {
        int ch = ks * 4 + kg;
        int sw = (ch ^ (m16 & 7)) << 3;
        f16x8_t a_0 = *(const f16x8_t*)&Ah[m16 * 256 + sw];
        f16x8_t a_1 = *(const f16x8_t*)&Ah[(16 + m16) * 256 + sw];
#pragma unroll
        for (int g = 0; g < 3; ++g) {
            size_t foff = ((size_t)ks * 48 + g * 16) * 512;
            f16x8_t b_h = *(const f16x8_t*)(b_p + foff);
            acc[0][g] = __builtin_amdgcn_mfma_f32_16x16x32_f16(a_0, b_h, acc[0][g], 0, 0, 0);
            acc[1][g] = __builtin_amdgcn_mfma_f32_16x16x32_f16(a_1, b_h, acc[1][g], 0, 0, 0);
        }
    }

    // fused GRU epilogue: C row=(lane>>4)*4+reg (batch m), col=lane&15 (unit)
    int mg = (lane >> 4) * 4;
    int tt = q * 16 + m16;
    float4 bs = b4[e * 256 + tt];
#pragma unroll
    for (int tl2 = 0; tl2 < 2; ++tl2) {
#pragma unroll
        for (int i = 0; i < 4; ++i) {
            int mr = tl2 * 16 + mg + i;
            if (mr < M) {
                int b = bids[mr];
                float x = hx[(size_t)b * 256 + tt];
                float r = sigm(acc[tl2][0][i] + bs.x);
                float u = sigm(acc[tl2][1][i] + bs.y);
                float n = tanhf(bs.z + r * (acc[tl2][2][i] + bs.w));
                out[(size_t)b * 256 + tt] = u * x + (1.0f - u) * n;
            }
        }
    }
}

// --- fallback: correct but slow, if ws too small --------------------------
__global__ void k_naive(const float* __restrict__ inp, const float* __restrict__ hx,
                        const float* __restrict__ w, const float* __restrict__ b_ih,
                        const float* __restrict__ b_hh, float* __restrict__ out) {
    int b = blockIdx.x;
    int t = threadIdx.x;
    __shared__ float sx[H_N];
    __shared__ int sidx;
    if (t == 0) {
        int idx = 0;
        for (int i = 0; i < I_N; ++i)
            if (inp[b * I_N + i] > 0.5f) idx = i;
        sidx = idx;
    }
    sx[t] = hx[b * H_N + t];
    __syncthreads();
    int i = sidx;
    float a0 = 0.f, a1 = 0.f, a2 = 0.f;
    for (int h = 0; h < H_N; ++h) {
        float xv = sx[h];
        a0 = fmaf(w[(t * H_N + h) * I_N + i], xv, a0);
        a1 = fmaf(w[((256 + t) * H_N + h) * I_N + i], xv, a1);
        a2 = fmaf(w[((512 + t) * H_N + h) * I_N + i], xv, a2);
    }
    float r = sigm(b_ih[t * I_N + i] + a0 + b_hh[t * I_N + i]);
    float u = sigm(b_ih[(256 + t) * I_N + i] + a1 + b_hh[(256 + t) * I_N + i]);
    float n = tanhf(b_ih[(512 + t) * I_N + i] + r * (a2 + b_hh[(512 + t) * I_N + i]));
    out[b * H_N + t] = u * sx[t] + (1.0f - u) * n;
}

extern "C" void kernel_launch(void* const* d_in, const int* in_sizes, int n_in,
                              void* d_out, int out_size, void* d_ws, size_t ws_size,
                              hipStream_t stream) {
    const float* inp  = (const float*)d_in[0];
    const float* hx   = (const float*)d_in[1];
    const float* w    = (const float*)d_in[2];
    const float* b_ih = (const float*)d_in[3];
    const float* b_hh = (const float*)d_in[4];
    float* out = (float*)d_out;

    if (ws_size < (size_t)WS_NEEDED) {
        k_naive<<<B_N, H_N, 0, stream>>>(inp, hx, w, b_ih, b_hh, out);
        return;
    }

    char* ws = (char*)d_ws;
    int* idx_arr = (int*)(ws + WS_IDX);
    int* slots   = (int*)(ws + WS_SLOTS);
    int* sorted  = (int*)(ws + WS_SORTED);
    float4* b4   = (float4*)(ws + WS_B4);
    unsigned short* w5 = (unsigned short*)(ws + WS_W5);

    k_aux<<<816, 256, 0, stream>>>(w, w5, b_ih, b_hh, b4, inp, idx_arr);
    k_plan<<<1, 512, 0, stream>>>(idx_arr, slots, sorted);
    k_gemm_mfma<<<dim3(NSLOT_TOT, 4), 256, 0, stream>>>(w5, hx, b4,
                                                        sorted, slots, out);
}

// Round 10
// 28.218 us; speedup vs baseline: 1.9072x; 1.0724x over previous
//
#include <hip/hip_runtime.h>
#include <math.h>

#define B_N 4096
#define H_N 256
#define I_N 32
#define G3  768
#define NSEG 16                  // idx segments (16 blocks x 256 rows)
#define BKROW 4096               // bucket row stride (ints)

// ---- workspace layout (bytes) ----
#define WS_SC      0             // 16*32 ints = 2 KB (per-segment expert counts)
#define WS_BUCKET  2048          // 32*4096 ints = 512 KB
#define WS_B4      526336        // 32*256 float4 = 128 KB
#define WS_W5      657408        // 32*768*256 fp16 = 12.58 MB (fragment-major)
#define WS_NEEDED  13240320

typedef __attribute__((ext_vector_type(8))) _Float16 f16x8_t;
typedef __attribute__((ext_vector_type(4))) float f32x4_t;

__device__ __forceinline__ float sigm(float x) { return 1.0f / (1.0f + __expf(-x)); }
__device__ __forceinline__ float tanh_fast(float x) {
    float xc = fminf(fmaxf(x, -15.f), 15.f);
    float t = __expf(2.f * xc);
    return (t - 1.f) / (t + 1.f);
}

// --- fused aux: repack (768 blk) | bias4 (32 blk) | idx->bucket (16 blk) --
// repack: w[g3][h][e] fp32 -> fragment-major SINGLE fp16:
//   w5[(e*8+ks)*48 + rowgrp][lane] as uint4; lane = kg*16+m16 holds
//   row = rowgrp*16+m16, k = ks*32+kg*8+0..7.  Each MFMA B-fragment is a
//   contiguous 1 KB block read as lane-consecutive dwordx4 (no gather).
// idx: segment seg owns rows [seg*256,+256); block-local LDS ranks ->
//   bucket[e][seg*256+lp]; counts -> sc[seg][e]. No global atomics/memset.
__global__ __launch_bounds__(256) void k_aux(
    const float* __restrict__ w, unsigned short* __restrict__ w5,
    const float* __restrict__ b_ih, const float* __restrict__ b_hh,
    float4* __restrict__ b4,
    const float* __restrict__ inp, int* __restrict__ sc,
    int* __restrict__ bucket)
{
    int bid = blockIdx.x;
    int t = threadIdx.x;
    if (bid < 768) {
        // ---- repack: 8 g3-rows x 32 h x 32 e per block ----
        __shared__ float tl[8 * 1057];      // odd row stride: bank-spread
        int r0 = (bid >> 3) * 8;            // g3-row base (0..760)
        int ks = bid & 7;                   // h-tile = ks*32
#pragma unroll
        for (int it = 0; it < 8; ++it) {
            int f4 = it * 256 + t;          // 0..2047
            int e4 = (f4 & 7) * 4, hh = (f4 >> 3) & 31, r = f4 >> 8;
            float4 v = *(const float4*)(w + ((size_t)(r0 + r) * 256 + ks * 32 + hh) * 32 + e4);
            int bse = r * 1057 + hh * 33 + e4;
            tl[bse] = v.x; tl[bse + 1] = v.y; tl[bse + 2] = v.z; tl[bse + 3] = v.w;
        }
        __syncthreads();
        int rowgrp = r0 >> 4;
        int mbase = r0 & 15;                // 0 or 8
#pragma unroll
        for (int it = 0; it < 4; ++it) {
            int c = it * 256 + t;           // 0..1023
            int m8 = c & 7, kg = (c >> 3) & 3, e = c >> 5;
            union { _Float16 h[8]; uint4 v; } hi;
#pragma unroll
            for (int t8 = 0; t8 < 8; ++t8) {
                float f = tl[m8 * 1057 + (kg * 8 + t8) * 33 + e];
                hi.h[t8] = (_Float16)f;
            }
            size_t chunk = ((size_t)(e * 8 + ks) * 48 + rowgrp) * 64 + kg * 16 + mbase + m8;
            ((uint4*)w5)[chunk] = hi.v;
        }
    } else if (bid < 800) {
        // ---- bias4: b4[e][tt] = {r_sum, u_sum, n_ih, n_hh} ----
        int bb = bid - 768;
        int e = t & 31;
        int tt = bb * 8 + (t >> 5);
        float r = b_ih[tt * 32 + e] + b_hh[tt * 32 + e];
        float u = b_ih[(256 + tt) * 32 + e] + b_hh[(256 + tt) * 32 + e];
        float ni = b_ih[(512 + tt) * 32 + e];
        float nh = b_hh[(512 + tt) * 32 + e];
        float4 o = {r, u, ni, nh};
        b4[e * 256 + tt] = o;
    } else {
        // ---- one-hot -> expert index, segment-local bucket ----
        __shared__ int lhist[32];
        int seg = bid - 800;
        if (t < 32) lhist[t] = 0;
        __syncthreads();
        int b = seg * 256 + t;
        const float4* p = (const float4*)(inp + (size_t)b * I_N);
        int idx = 0;
#pragma unroll
        for (int k = 0; k < 8; ++k) {
            float4 v = p[k];
            if (v.x > 0.5f) idx = k * 4 + 0;
            if (v.y > 0.5f) idx = k * 4 + 1;
            if (v.z > 0.5f) idx = k * 4 + 2;
            if (v.w > 0.5f) idx = k * 4 + 3;
        }
        int lp = atomicAdd(&lhist[idx], 1);
        bucket[idx * BKROW + seg * 256 + lp] = b;
        __syncthreads();
        if (t < 32) sc[seg * 32 + t] = lhist[t];
    }
}

// --- grouped MFMA GEMM + inline plan + fused GRU epilogue, M=32 -----------
// Schedule is a pure function of sc[]: bucket bkt = blockIdx.x&7 owns experts
// {bkt, bkt+8, bkt+16, bkt+24} (XCD-affine: 272%8==0). j-slots grid-stride
// to cover worst-case skew. Batch ids resolved by 16-step segment scan.
__global__ __launch_bounds__(256) void k_gemm_mfma(
    const unsigned short* __restrict__ w5,
    const float* __restrict__ hx, const float4* __restrict__ b4,
    const int* __restrict__ sc, const int* __restrict__ bucket,
    float* __restrict__ out)
{
    int bkt = blockIdx.x & 7, j0 = blockIdx.x >> 3;   // j0 in 0..33
    int t = threadIdx.x;

    // chunk counts for this bucket's 4 experts
    int tot[4], nch[4];
#pragma unroll
    for (int i = 0; i < 4; ++i) {
        int e = bkt + 8 * i, s = 0;
#pragma unroll
        for (int j = 0; j < NSEG; ++j) s += sc[j * 32 + e];
        tot[i] = s; nch[i] = (s + 31) >> 5;
    }
    int c1 = nch[0], c2 = c1 + nch[1], c3 = c2 + nch[2], ntot = c3 + nch[3];

    __shared__ _Float16 Ah[32 * 256];   // 16 KB
    __shared__ int bids[32];

    for (int jj = j0; jj < ntot; jj += 34) {
        int ei, ch;
        if (jj < c1)      { ei = 0; ch = jj; }
        else if (jj < c2) { ei = 1; ch = jj - c1; }
        else if (jj < c3) { ei = 2; ch = jj - c2; }
        else              { ei = 3; ch = jj - c3; }
        int e = bkt + 8 * ei;
        int M = tot[ei] - ch * 32; if (M > 32) M = 32;

        // resolve batch id for this thread's row via segment scan
        int row = t >> 3, c8 = t & 7;
        int b = -1;
        if (row < M) {
            int rank = ch * 32 + row;
            int acc = 0, seg = 0, off = 0;
#pragma unroll
            for (int j = 0; j < NSEG; ++j) {
                int c = sc[j * 32 + e];
                if (rank >= acc && rank < acc + c) { seg = j; off = rank - acc; }
                acc += c;
            }
            b = bucket[e * BKROW + seg * 256 + off];
        }
        if (c8 == 0) bids[row] = b;

        // stage A: row (batch), c8 owns k in [c8*32, +32), fp32 -> fp16
        if (b >= 0) {
            const float* src = hx + ((size_t)b << 8) + c8 * 32;
            float fv[32];
#pragma unroll
            for (int p = 0; p < 8; ++p)
                *(float4*)&fv[p * 4] = *(const float4*)(src + p * 4);
#pragma unroll
            for (int p = 0; p < 4; ++p) {
                union { _Float16 h[8]; uint4 v; } hu;
#pragma unroll
                for (int jj2 = 0; jj2 < 8; ++jj2)
                    hu.h[jj2] = (_Float16)fv[p * 8 + jj2];
                int col = (c8 * 4 + p) ^ (row & 7);
                *(uint4*)&Ah[row * 256 + col * 8] = hu.v;
            }
        } else {
            uint4 z = {0, 0, 0, 0};
#pragma unroll
            for (int p = 0; p < 4; ++p) {
                int col = (c8 * 4 + p) ^ (row & 7);
                *(uint4*)&Ah[row * 256 + col * 8] = z;
            }
        }
        __syncthreads();

        int lane = t & 63, wv = t >> 6;
        int m16 = lane & 15, kg = lane >> 4;
        int q = blockIdx.y * 4 + wv;         // unit group 0..15

        f32x4_t acc2[2][3];
#pragma unroll
        for (int tl2 = 0; tl2 < 2; ++tl2)
#pragma unroll
            for (int g = 0; g < 3; ++g) acc2[tl2][g] = (f32x4_t){0.f, 0.f, 0.f, 0.f};

        // fragment id = (e*8+ks)*48 + g*16 + q; 512 halfs per fragment
        const unsigned short* b_p = w5 + ((size_t)(e * 8) * 48 + q) * 512 + (size_t)lane * 8;

#pragma unroll
        for (int ks = 0; ks < 8; ++ks) {
            int chs = ks * 4 + kg;
            int sw = (chs ^ (m16 & 7)) << 3;
            f16x8_t a_0 = *(const f16x8_t*)&Ah[m16 * 256 + sw];
            f16x8_t a_1 = *(const f16x8_t*)&Ah[(16 + m16) * 256 + sw];
#pragma unroll
            for (int g = 0; g < 3; ++g) {
                size_t foff = ((size_t)ks * 48 + g * 16) * 512;
                f16x8_t b_h = *(const f16x8_t*)(b_p + foff);
                acc2[0][g] = __builtin_amdgcn_mfma_f32_16x16x32_f16(a_0, b_h, acc2[0][g], 0, 0, 0);
                acc2[1][g] = __builtin_amdgcn_mfma_f32_16x16x32_f16(a_1, b_h, acc2[1][g], 0, 0, 0);
            }
        }

        // fused GRU epilogue: C row=(lane>>4)*4+reg (batch), col=lane&15 (unit)
        int mg = (lane >> 4) * 4;
        int tt = q * 16 + m16;
        float4 bs = b4[e * 256 + tt];
#pragma unroll
        for (int tl2 = 0; tl2 < 2; ++tl2) {
#pragma unroll
            for (int i = 0; i < 4; ++i) {
                int mr = tl2 * 16 + mg + i;
                if (mr < M) {
                    int bb = bids[mr];
                    float x = hx[(size_t)bb * 256 + tt];
                    float r = sigm(acc2[tl2][0][i] + bs.x);
                    float u = sigm(acc2[tl2][1][i] + bs.y);
                    float n = tanh_fast(bs.z + r * (acc2[tl2][2][i] + bs.w));
                    out[(size_t)bb * 256 + tt] = u * x + (1.0f - u) * n;
                }
            }
        }
        __syncthreads();   // protect Ah/bids before next chunk restage
    }
}

// --- fallback: correct but slow, if ws too small --------------------------
__global__ void k_naive(const float* __restrict__ inp, const float* __restrict__ hx,
                        const float* __restrict__ w, const float* __restrict__ b_ih,
                        const float* __restrict__ b_hh, float* __restrict__ out) {
    int b = blockIdx.x;
    int t = threadIdx.x;
    __shared__ float sx[H_N];
    __shared__ int sidx;
    if (t == 0) {
        int idx = 0;
        for (int i = 0; i < I_N; ++i)
            if (inp[b * I_N + i] > 0.5f) idx = i;
        sidx = idx;
    }
    sx[t] = hx[b * H_N + t];
    __syncthreads();
    int i = sidx;
    float a0 = 0.f, a1 = 0.f, a2 = 0.f;
    for (int h = 0; h < H_N; ++h) {
        float xv = sx[h];
        a0 = fmaf(w[(t * H_N + h) * I_N + i], xv, a0);
        a1 = fmaf(w[((256 + t) * H_N + h) * I_N + i], xv, a1);
        a2 = fmaf(w[((512 + t) * H_N + h) * I_N + i], xv, a2);
    }
    float r = sigm(b_ih[t * I_N + i] + a0 + b_hh[t * I_N + i]);
    float u = sigm(b_ih[(256 + t) * I_N + i] + a1 + b_hh[(256 + t) * I_N + i]);
    float n = tanhf(b_ih[(512 + t) * I_N + i] + r * (a2 + b_hh[(512 + t) * I_N + i]));
    out[b * H_N + t] = u * sx[t] + (1.0f - u) * n;
}

extern "C" void kernel_launch(void* const* d_in, const int* in_sizes, int n_in,
                              void* d_out, int out_size, void* d_ws, size_t ws_size,
                              hipStream_t stream) {
    const float* inp  = (const float*)d_in[0];
    const float* hx   = (const float*)d_in[1];
    const float* w    = (const float*)d_in[2];
    const float* b_ih = (const float*)d_in[3];
    const float* b_hh = (const float*)d_in[4];
    float* out = (float*)d_out;

    if (ws_size < (size_t)WS_NEEDED) {
        k_naive<<<B_N, H_N, 0, stream>>>(inp, hx, w, b_ih, b_hh, out);
        return;
    }

    char* ws = (char*)d_ws;
    int* sc     = (int*)(ws + WS_SC);
    int* bucket = (int*)(ws + WS_BUCKET);
    float4* b4  = (float4*)(ws + WS_B4);
    unsigned short* w5 = (unsigned short*)(ws + WS_W5);

    k_aux<<<816, 256, 0, stream>>>(w, w5, b_ih, b_hh, b4, inp, sc, bucket);
    k_gemm_mfma<<<dim3(272, 4), 256, 0, stream>>>(w5, hx, b4, sc, bucket, out);
}

// Round 11
// 27.161 us; speedup vs baseline: 1.9815x; 1.0389x over previous
//
#include <hip/hip_runtime.h>
#include <math.h>

#define B_N 4096
#define H_N 256
#define I_N 32
#define G3  768
#define NSEG 16                  // idx segments (16 blocks x 256 rows)
#define BKROW 4096               // bucket row stride (ints)

// ---- workspace layout (bytes) ----
#define WS_SC      0             // 16*32 ints = 2 KB (per-segment expert counts)
#define WS_BUCKET  2048          // 32*4096 ints = 512 KB
#define WS_B4      526336        // 32*256 float4 = 128 KB
#define WS_W5      657408        // 32*768*256 fp16 = 12.58 MB (fragment-major)
#define WS_NEEDED  13240320

typedef __attribute__((ext_vector_type(8))) _Float16 f16x8_t;
typedef __attribute__((ext_vector_type(4))) float f32x4_t;

__device__ __forceinline__ float sigm(float x) { return 1.0f / (1.0f + __expf(-x)); }
__device__ __forceinline__ float tanh_fast(float x) {
    float xc = fminf(fmaxf(x, -15.f), 15.f);
    float t = __expf(2.f * xc);
    return (t - 1.f) / (t + 1.f);
}

// --- fused aux: repack (768 blk) | bias4 (32 blk) | idx->bucket (16 blk) --
// repack: w[g3][h][e] fp32 -> fragment-major SINGLE fp16:
//   w5[(e*8+ks)*48 + rowgrp][lane] as uint4; lane = kg*16+m16 holds
//   row = rowgrp*16+m16, k = ks*32+kg*8+0..7.  Each MFMA B-fragment is a
//   contiguous 1 KB block read as lane-consecutive dwordx4 (no gather).
// idx: segment seg owns rows [seg*256,+256); block-local LDS ranks ->
//   bucket[e][seg*256+lp]; counts -> sc[seg][e]. No global atomics/memset.
__global__ __launch_bounds__(256) void k_aux(
    const float* __restrict__ w, unsigned short* __restrict__ w5,
    const float* __restrict__ b_ih, const float* __restrict__ b_hh,
    float4* __restrict__ b4,
    const float* __restrict__ inp, int* __restrict__ sc,
    int* __restrict__ bucket)
{
    int bid = blockIdx.x;
    int t = threadIdx.x;
    if (bid < 768) {
        // ---- repack: 8 g3-rows x 32 h x 32 e per block ----
        __shared__ float tl[8 * 1057];      // odd row stride: bank-spread
        int r0 = (bid >> 3) * 8;            // g3-row base (0..760)
        int ks = bid & 7;                   // h-tile = ks*32
#pragma unroll
        for (int it = 0; it < 8; ++it) {
            int f4 = it * 256 + t;          // 0..2047
            int e4 = (f4 & 7) * 4, hh = (f4 >> 3) & 31, r = f4 >> 8;
            float4 v = *(const float4*)(w + ((size_t)(r0 + r) * 256 + ks * 32 + hh) * 32 + e4);
            int bse = r * 1057 + hh * 33 + e4;
            tl[bse] = v.x; tl[bse + 1] = v.y; tl[bse + 2] = v.z; tl[bse + 3] = v.w;
        }
        __syncthreads();
        int rowgrp = r0 >> 4;
        int mbase = r0 & 15;                // 0 or 8
#pragma unroll
        for (int it = 0; it < 4; ++it) {
            int c = it * 256 + t;           // 0..1023
            int m8 = c & 7, kg = (c >> 3) & 3, e = c >> 5;
            union { _Float16 h[8]; uint4 v; } hi;
#pragma unroll
            for (int t8 = 0; t8 < 8; ++t8) {
                float f = tl[m8 * 1057 + (kg * 8 + t8) * 33 + e];
                hi.h[t8] = (_Float16)f;
            }
            size_t chunk = ((size_t)(e * 8 + ks) * 48 + rowgrp) * 64 + kg * 16 + mbase + m8;
            ((uint4*)w5)[chunk] = hi.v;
        }
    } else if (bid < 800) {
        // ---- bias4: b4[e][tt] = {r_sum, u_sum, n_ih, n_hh} ----
        int bb = bid - 768;
        int e = t & 31;
        int tt = bb * 8 + (t >> 5);
        float r = b_ih[tt * 32 + e] + b_hh[tt * 32 + e];
        float u = b_ih[(256 + tt) * 32 + e] + b_hh[(256 + tt) * 32 + e];
        float ni = b_ih[(512 + tt) * 32 + e];
        float nh = b_hh[(512 + tt) * 32 + e];
        float4 o = {r, u, ni, nh};
        b4[e * 256 + tt] = o;
    } else {
        // ---- one-hot -> expert index, segment-local bucket ----
        __shared__ int lhist[32];
        int seg = bid - 800;
        if (t < 32) lhist[t] = 0;
        __syncthreads();
        int b = seg * 256 + t;
        const float4* p = (const float4*)(inp + (size_t)b * I_N);
        int idx = 0;
#pragma unroll
        for (int k = 0; k < 8; ++k) {
            float4 v = p[k];
            if (v.x > 0.5f) idx = k * 4 + 0;
            if (v.y > 0.5f) idx = k * 4 + 1;
            if (v.z > 0.5f) idx = k * 4 + 2;
            if (v.w > 0.5f) idx = k * 4 + 3;
        }
        int lp = atomicAdd(&lhist[idx], 1);
        bucket[idx * BKROW + seg * 256 + lp] = b;
        __syncthreads();
        if (t < 32) sc[seg * 32 + t] = lhist[t];
    }
}

// --- grouped MFMA GEMM + inline plan + fused GRU epilogue, M=16 -----------
// bucket bkt = blockIdx.x&7 owns experts {bkt,+8,+16,+24} (XCD-affine:
// 272%8==0, grid-y preserves phase). j-slots grid-stride for skew. B
// fragments software-pipelined (depth 2, first loads issued before the
// A-stage barrier). Epilogue x read back from LDS A (fp16-rounded hx).
__global__ __launch_bounds__(256, 4) void k_gemm_mfma(
    const unsigned short* __restrict__ w5,
    const float* __restrict__ hx, const float4* __restrict__ b4,
    const int* __restrict__ sc, const int* __restrict__ bucket,
    float* __restrict__ out)
{
    int bkt = blockIdx.x & 7, j0 = blockIdx.x >> 3;   // j0 in 0..33
    int t = threadIdx.x;

    // chunk counts for this bucket's 4 experts (all uniform scalar math)
    int tot0 = 0, tot1 = 0, tot2 = 0, tot3 = 0;
#pragma unroll
    for (int j = 0; j < NSEG; ++j) {
        tot0 += sc[j * 32 + bkt];
        tot1 += sc[j * 32 + bkt + 8];
        tot2 += sc[j * 32 + bkt + 16];
        tot3 += sc[j * 32 + bkt + 24];
    }
    int c1 = (tot0 + 15) >> 4;
    int c2 = c1 + ((tot1 + 15) >> 4);
    int c3 = c2 + ((tot2 + 15) >> 4);
    int ntot = c3 + ((tot3 + 15) >> 4);

    __shared__ _Float16 Ah[16 * 256];   // 8 KB
    __shared__ int bids[16];

    int lane = t & 63, wv = t >> 6;
    int m16 = lane & 15, kg = lane >> 4;
    int q = blockIdx.y * 4 + wv;         // unit group 0..15

    for (int jj = j0; jj < ntot; jj += 34) {
        int ei = (jj < c1) ? 0 : (jj < c2) ? 1 : (jj < c3) ? 2 : 3;
        int ch = (jj < c1) ? jj : (jj < c2) ? jj - c1 : (jj < c3) ? jj - c2 : jj - c3;
        int te = (jj < c1) ? tot0 : (jj < c2) ? tot1 : (jj < c3) ? tot2 : tot3;
        int e = bkt + 8 * ei;
        int M = te - ch * 16; if (M > 16) M = 16;

        // fragment base; issue ks=0 loads NOW (hide under A-stage + barrier)
        const unsigned short* b_p = w5 + ((size_t)(e * 8) * 48 + q) * 512 + (size_t)lane * 8;
        f16x8_t bc0 = *(const f16x8_t*)(b_p);
        f16x8_t bc1 = *(const f16x8_t*)(b_p + (size_t)16 * 512);
        f16x8_t bc2 = *(const f16x8_t*)(b_p + (size_t)32 * 512);

        // resolve batch id via segment scan (sc reads are uniform/scalar)
        int row = t >> 4, c16 = t & 15;
        int b = -1;
        if (row < M) {
            int rank = ch * 16 + row;
            int acc = 0, seg = 0, off = 0;
#pragma unroll
            for (int j = 0; j < NSEG; ++j) {
                int c = sc[j * 32 + e];
                if (rank >= acc && rank < acc + c) { seg = j; off = rank - acc; }
                acc += c;
            }
            b = bucket[e * BKROW + seg * 256 + off];
        }
        if (c16 == 0) bids[row] = b;

        // stage A: row (batch), c16 owns k in [c16*16, +16), fp32 -> fp16
        if (b >= 0) {
            const float* src = hx + ((size_t)b << 8) + c16 * 16;
            float fv[16];
#pragma unroll
            for (int p = 0; p < 4; ++p)
                *(float4*)&fv[p * 4] = *(const float4*)(src + p * 4);
#pragma unroll
            for (int p = 0; p < 2; ++p) {
                union { _Float16 h[8]; uint4 v; } hu;
#pragma unroll
                for (int jj2 = 0; jj2 < 8; ++jj2)
                    hu.h[jj2] = (_Float16)fv[p * 8 + jj2];
                int col = (c16 * 2 + p) ^ (row & 7);
                *(uint4*)&Ah[row * 256 + col * 8] = hu.v;
            }
        } else {
            uint4 z = {0, 0, 0, 0};
#pragma unroll
            for (int p = 0; p < 2; ++p) {
                int col = (c16 * 2 + p) ^ (row & 7);
                *(uint4*)&Ah[row * 256 + col * 8] = z;
            }
        }
        __syncthreads();

        f32x4_t ac0 = {0.f, 0.f, 0.f, 0.f};
        f32x4_t ac1 = {0.f, 0.f, 0.f, 0.f};
        f32x4_t ac2 = {0.f, 0.f, 0.f, 0.f};

        // K-loop: depth-2 pipeline (load ks+1 while MFMAing ks)
#pragma unroll
        for (int ks = 0; ks < 8; ++ks) {
            f16x8_t bn0 = bc0, bn1 = bc1, bn2 = bc2;
            if (ks < 7) {
                const unsigned short* np = b_p + (size_t)(ks + 1) * 48 * 512;
                bn0 = *(const f16x8_t*)(np);
                bn1 = *(const f16x8_t*)(np + (size_t)16 * 512);
                bn2 = *(const f16x8_t*)(np + (size_t)32 * 512);
            }
            int sw = ((ks * 4 + kg) ^ (m16 & 7)) << 3;
            f16x8_t a0 = *(const f16x8_t*)&Ah[m16 * 256 + sw];
            ac0 = __builtin_amdgcn_mfma_f32_16x16x32_f16(a0, bc0, ac0, 0, 0, 0);
            ac1 = __builtin_amdgcn_mfma_f32_16x16x32_f16(a0, bc1, ac1, 0, 0, 0);
            ac2 = __builtin_amdgcn_mfma_f32_16x16x32_f16(a0, bc2, ac2, 0, 0, 0);
            bc0 = bn0; bc1 = bn1; bc2 = bn2;
        }

        // fused GRU epilogue: C row=(lane>>4)*4+i (batch), col=lane&15 (unit)
        int mg = (lane >> 4) * 4;
        int tt = q * 16 + m16;
        float4 bs = b4[e * 256 + tt];
#pragma unroll
        for (int i = 0; i < 4; ++i) {
            int mr = mg + i;
            if (mr < M) {
                int bb = bids[mr];
                // x = staged fp16(hx[bb][tt]) from LDS (k-space == unit-space)
                int xc = ((tt >> 3) ^ (mr & 7)) * 8 + (tt & 7);
                float x = (float)Ah[mr * 256 + xc];
                float r = sigm(ac0[i] + bs.x);
                float u = sigm(ac1[i] + bs.y);
                float n = tanh_fast(bs.z + r * (ac2[i] + bs.w));
                out[(size_t)bb * 256 + tt] = u * x + (1.0f - u) * n;
            }
        }
        __syncthreads();   // protect Ah/bids before next chunk restage
    }
}

// --- fallback: correct but slow, if ws too small --------------------------
__global__ void k_naive(const float* __restrict__ inp, const float* __restrict__ hx,
                        const float* __restrict__ w, const float* __restrict__ b_ih,
                        const float* __restrict__ b_hh, float* __restrict__ out) {
    int b = blockIdx.x;
    int t = threadIdx.x;
    __shared__ float sx[H_N];
    __shared__ int sidx;
    if (t == 0) {
        int idx = 0;
        for (int i = 0; i < I_N; ++i)
            if (inp[b * I_N + i] > 0.5f) idx = i;
        sidx = idx;
    }
    sx[t] = hx[b * H_N + t];
    __syncthreads();
    int i = sidx;
    float a0 = 0.f, a1 = 0.f, a2 = 0.f;
    for (int h = 0; h < H_N; ++h) {
        float xv = sx[h];
        a0 = fmaf(w[(t * H_N + h) * I_N + i], xv, a0);
        a1 = fmaf(w[((256 + t) * H_N + h) * I_N + i], xv, a1);
        a2 = fmaf(w[((512 + t) * H_N + h) * I_N + i], xv, a2);
    }
    float r = sigm(b_ih[t * I_N + i] + a0 + b_hh[t * I_N + i]);
    float u = sigm(b_ih[(256 + t) * I_N + i] + a1 + b_hh[(256 + t) * I_N + i]);
    float n = tanhf(b_ih[(512 + t) * I_N + i] + r * (a2 + b_hh[(512 + t) * I_N + i]));
    out[b * H_N + t] = u * sx[t] + (1.0f - u) * n;
}

extern "C" void kernel_launch(void* const* d_in, const int* in_sizes, int n_in,
                              void* d_out, int out_size, void* d_ws, size_t ws_size,
                              hipStream_t stream) {
    const float* inp  = (const float*)d_in[0];
    const float* hx   = (const float*)d_in[1];
    const float* w    = (const float*)d_in[2];
    const float* b_ih = (const float*)d_in[3];
    const float* b_hh = (const float*)d_in[4];
    float* out = (float*)d_out;

    if (ws_size < (size_t)WS_NEEDED) {
        k_naive<<<B_N, H_N, 0, stream>>>(inp, hx, w, b_ih, b_hh, out);
        return;
    }

    char* ws = (char*)d_ws;
    int* sc     = (int*)(ws + WS_SC);
    int* bucket = (int*)(ws + WS_BUCKET);
    float4* b4  = (float4*)(ws + WS_B4);
    unsigned short* w5 = (unsigned short*)(ws + WS_W5);

    k_aux<<<816, 256, 0, stream>>>(w, w5, b_ih, b_hh, b4, inp, sc, bucket);
    k_gemm_mfma<<<dim3(272, 4), 256, 0, stream>>>(w5, hx, b4, sc, bucket, out);
}